// Round 8
// baseline (711.370 us; speedup 1.0000x reference)
//
#include <hip/hip_runtime.h>
#include <stdint.h>

#define N_TOK 262144
#define DIM 64
#define K_CODES 1024
#define OUT_LOSS_OFF (N_TOK * DIM)      // 16777216
#define OUT_IDX_OFF (N_TOK * DIM + 1)   // 16777217

// Hi-only screen error: |screen - real| <= (2^-11 z-cvt + 2^-11 w-cvt)
// * ||2z||*||w|| + fp32 accum ~ 1.9e-4 (||z|| <= 11.5). Candidate rule
// needs THR > 2*eps_s = 3.8e-4. THR = 6.5e-4 (1.7x headroom).
// Screen works on acch = 1024*(dot - w2) directly (exact pow2 scale,
// order-REVERSED): candidate <=> acch >= M1 - 1024*THR = M1 - 0.666.
#define THRA 0.666f
#define WCAP 256

typedef _Float16 half8 __attribute__((ext_vector_type(8)));
typedef float f32x4 __attribute__((ext_vector_type(4)));
typedef unsigned int uint32x4 __attribute__((ext_vector_type(4)));

// ---- staged codebook: module-scope device global (NOT d_ws). ----
// R8 post-mortem: R7 wrote 135KB into d_ws assuming ws_size >= 139264;
// prior rounds only ever used 8B, so that was an unverified OOB hazard and
// the likely cause of the container fault. A __device__ global is statically
// allocated at module load -- no hipMalloc, no graph-capture issue, no
// ws_size assumption. d_ws returns to its proven 8-byte loss role.
#define GW_WF16 0                  // fp16(w*1024): 1024 rows x 128 B
#define GW_W2 131072               // float[1024] ||w_c||^2
__device__ __align__(16) char g_wprep[131072 + 4096];

// ---- LDS layout (byte offsets) ---- total ~26 KB -> 2 blocks/CU
// (thread-limited 2048/CU) = 8 waves/SIMD (R6 was 4: 153KB LDS).
#define SM_SW2 0          // float[1024] ||w||^2 (exact, for exact_dist)
#define SM_SVT 4096       // float[16][68] svmT[c15][ct] = -1024*w2, padded
#define SM_SZ2 8448       // float[256] ||z||^2
#define SM_WL 9472        // u32[16][WCAP] per-wave candidate lists
#define SM_WC 25856       // int[16] per-wave candidate counters
#define SM_RED 25920      // double[16] loss partials
#define SM_BYTES 26048

// numpy pairwise sum of squares over 64 contiguous fp32, STREAMING form:
// identical operation order to the reference pairwise sum (8 accumulators,
// unroll-8, paired combine) but never holds more than 16 values live.
__device__ __forceinline__ float np_sumsq64_stream(const float4* p) {
#pragma clang fp contract(off)
  float r[8];
  {
    float4 a = p[0], b = p[1];
    r[0] = a.x * a.x;
    r[1] = a.y * a.y;
    r[2] = a.z * a.z;
    r[3] = a.w * a.w;
    r[4] = b.x * b.x;
    r[5] = b.y * b.y;
    r[6] = b.z * b.z;
    r[7] = b.w * b.w;
  }
#pragma unroll
  for (int i = 1; i < 8; ++i) {
    float4 a = p[2 * i], b = p[2 * i + 1];
    r[0] += a.x * a.x;
    r[1] += a.y * a.y;
    r[2] += a.z * a.z;
    r[3] += a.w * a.w;
    r[4] += b.x * b.x;
    r[5] += b.y * b.y;
    r[6] += b.z * b.z;
    r[7] += b.w * b.w;
  }
  return ((r[0] + r[1]) + (r[2] + r[3])) + ((r[4] + r[5]) + (r[6] + r[7]));
}

// The ORIGINAL bit-exact distance: d = fl(fl(s_z2+s_w2) - chain64((2z)*w)),
// sequential ascending k. Matches numpy/BLAS exactly -> argmin-identical.
__device__ __forceinline__ float exact_dist(const float* __restrict__ z,
                                            long long t, int c,
                                            const float* __restrict__ w,
                                            float s_z2v, float w2) {
  const float4* zp = (const float4*)(z + (size_t)t * DIM);
  const float4* wp = (const float4*)(w + (size_t)c * DIM);
  float a = 0.f;
#pragma unroll
  for (int i = 0; i < 16; ++i) {
    float4 zv = zp[i];
    float4 pv = wp[i];
    a = __builtin_fmaf(zv.x + zv.x, pv.x, a);
    a = __builtin_fmaf(zv.y + zv.y, pv.y, a);
    a = __builtin_fmaf(zv.z + zv.z, pv.z, a);
    a = __builtin_fmaf(zv.w + zv.w, pv.w, a);
  }
  return (s_z2v + w2) - a;
}

// Hi-only MFMA A-frag from 8 z floats: fp16(2z).
__device__ __forceinline__ void make_afrag_hi(float4 a, float4 b, half8& hi) {
  float v[8] = {a.x, a.y, a.z, a.w, b.x, b.y, b.z, b.w};
  uint32x4 uh;
#pragma unroll
  for (int j = 0; j < 4; ++j) {
    _Float16 h0 = (_Float16)(v[2 * j] + v[2 * j]);
    _Float16 h1 = (_Float16)(v[2 * j + 1] + v[2 * j + 1]);
    uh[j] = (unsigned)__builtin_bit_cast(unsigned short, h0) |
            ((unsigned)__builtin_bit_cast(unsigned short, h1) << 16);
  }
  hi = __builtin_bit_cast(half8, uh);
}

// ---------------- pre-kernel: codebook prep (once, 4 blocks) ----------------
// Per code c: ||w_c||^2 (numpy-pairwise exact order) + fp16(w*1024) row.
__global__ __launch_bounds__(256) void vq_pre_k(const float* __restrict__ w) {
#pragma clang fp contract(off)
  const int c = blockIdx.x * 256 + (int)threadIdx.x;
  const float4* wp = (const float4*)(w + (size_t)c * DIM);
  char* wf = g_wprep + GW_WF16 + (size_t)c * 128;
  float r[8];
#pragma unroll
  for (int ch = 0; ch < 8; ++ch) {
    float4 a = wp[2 * ch], b = wp[2 * ch + 1];
    float x[8] = {a.x, a.y, a.z, a.w, b.x, b.y, b.z, b.w};
    if (ch == 0) {
#pragma unroll
      for (int j = 0; j < 8; ++j) r[j] = x[j] * x[j];
    } else {
#pragma unroll
      for (int j = 0; j < 8; ++j) r[j] += x[j] * x[j];
    }
    uint32x4 pk;
#pragma unroll
    for (int j = 0; j < 4; ++j) {
      _Float16 h0 = (_Float16)(x[2 * j] * 1024.f);
      _Float16 h1 = (_Float16)(x[2 * j + 1] * 1024.f);
      pk[j] = (unsigned)__builtin_bit_cast(unsigned short, h0) |
              ((unsigned)__builtin_bit_cast(unsigned short, h1) << 16);
    }
    *(uint32x4*)(wf + ch * 16) = pk;  // linear layout
  }
  ((float*)(g_wprep + GW_W2))[c] =
      ((r[0] + r[1]) + (r[2] + r[3])) + ((r[4] + r[5]) + (r[6] + r[7]));
}

// ---------------- main: 256 tokens / 1024 threads / 16 waves ----------------
// Two-pass MFMA screen (pass1: per-token max; pass2: bit-identical recompute
// + candidate push), wave-local exact resolution. B-fragments stream from
// the L2-resident fp16 codebook (sequential 2KB/wave/iter sweep); LDS holds
// only norms + candidate lists -> 8 waves/SIMD for latency hiding.
__global__ __attribute__((amdgpu_flat_work_group_size(1024, 1024),
                          amdgpu_waves_per_eu(8, 8))) void vq_main_k(
    const float* __restrict__ z, const float* __restrict__ w,
    float* __restrict__ out, double* __restrict__ loss_acc) {
#pragma clang fp contract(off)
  __shared__ __align__(16) char smem[SM_BYTES];
  float* sw2 = (float*)(smem + SM_SW2);
  float* sz2 = (float*)(smem + SM_SZ2);
  double* red = (double*)(smem + SM_RED);

  const int tid = (int)threadIdx.x;
  const int lane = tid & 63;
  const int wid = tid >> 6;  // 16 waves

  unsigned* wl = (unsigned*)(smem + SM_WL) + wid * WCAP;
  int* wc = (int*)(smem + SM_WC) + wid;
  if (lane == 0) *wc = 0;

  // ---- prologue: stage norms (4KB + 4.4KB + 1KB) ----
  {
    float v = ((const float*)(g_wprep + GW_W2))[tid];
    sw2[tid] = v;
    // transposed, pre-negated screen C-init: svmT[c15][ct], pad 68 so the
    // 16 lanes' rows land on distinct bank groups (2-way max).
    ((float*)(smem + SM_SVT))[(tid & 15) * 68 + (tid >> 4)] = v * -1024.f;
  }
  if (tid < 256) {
    long long gt = (long long)blockIdx.x * 256 + tid;
    sz2[tid] = np_sumsq64_stream((const float4*)(z + (size_t)gt * DIM));
  }
  __syncthreads();

  // ---- per-wave screen: 16 tokens x all 1024 codes ----
  const int wtok = wid * 16;
  const int g = lane >> 4;    // k-group
  const int c15 = lane & 15;  // code-within-tile
  half8 ah0, ah1;
  {
    long long gA = ((long long)blockIdx.x * 256 + wtok + c15) * DIM;
    const float* zr = z + gA + g * 8;
    make_afrag_hi(*(const float4*)(zr), *(const float4*)(zr + 4), ah0);
    make_afrag_hi(*(const float4*)(zr + 32), *(const float4*)(zr + 36), ah1);
  }
  // B-frag global base: lane reads 16B at wf16[cc*128 + g*16] (+64 for b1)
  const char* wfg = g_wprep + GW_WF16 + c15 * 128 + g * 16;
  const char* svtrow = smem + SM_SVT + c15 * 272;  // 68 floats

  // pass 1: per-token max of acch (acch = 1024*(dot - w2c); larger = closer)
  float M1[4];
#pragma unroll
  for (int r = 0; r < 4; ++r) M1[r] = -3.4e38f;
  for (int ct4 = 0; ct4 < 16; ++ct4) {
    f32x4 vmq = *(const f32x4*)(svtrow + ct4 * 16);
#pragma unroll
    for (int j = 0; j < 4; ++j) {
      const uint32x4* p = (const uint32x4*)(wfg + (ct4 * 4 + j) * 2048);
      half8 b0 = __builtin_bit_cast(half8, p[0]);
      half8 b1 = __builtin_bit_cast(half8, p[4]);  // +64 B
      f32x4 acch = {vmq[j], vmq[j], vmq[j], vmq[j]};
      acch = __builtin_amdgcn_mfma_f32_16x16x32_f16(ah0, b0, acch, 0, 0, 0);
      acch = __builtin_amdgcn_mfma_f32_16x16x32_f16(ah1, b1, acch, 0, 0, 0);
#pragma unroll
      for (int r = 0; r < 4; ++r) M1[r] = fmaxf(M1[r], acch[r]);
    }
  }
  // butterfly all-reduce max over the 16 lanes sharing these 4 token rows
#pragma unroll
  for (int s = 1; s <= 8; s <<= 1) {
#pragma unroll
    for (int r = 0; r < 4; ++r) M1[r] = fmaxf(M1[r], __shfl_xor(M1[r], s, 64));
  }
  float thr[4];
#pragma unroll
  for (int r = 0; r < 4; ++r) thr[r] = M1[r] - THRA;

  // pass 2: recompute acch bit-identically; push candidates (tokloc<<10)|cc
  const int tb = g * 4;
  for (int ct4 = 0; ct4 < 16; ++ct4) {
    f32x4 vmq = *(const f32x4*)(svtrow + ct4 * 16);
#pragma unroll
    for (int j = 0; j < 4; ++j) {
      const int ct = ct4 * 4 + j;
      const uint32x4* p = (const uint32x4*)(wfg + ct * 2048);
      half8 b0 = __builtin_bit_cast(half8, p[0]);
      half8 b1 = __builtin_bit_cast(half8, p[4]);
      f32x4 acch = {vmq[j], vmq[j], vmq[j], vmq[j]};
      acch = __builtin_amdgcn_mfma_f32_16x16x32_f16(ah0, b0, acch, 0, 0, 0);
      acch = __builtin_amdgcn_mfma_f32_16x16x32_f16(ah1, b1, acch, 0, 0, 0);
      const int cc = (ct << 4) | c15;
      bool h0 = acch[0] >= thr[0];
      bool h1 = acch[1] >= thr[1];
      bool h2 = acch[2] >= thr[2];
      bool h3 = acch[3] >= thr[3];
      if (h0 | h1 | h2 | h3) {  // execz-skip in the common case
        if (h0) {
          int q = atomicAdd(wc, 1);
          if (q < WCAP) wl[q] = (unsigned)(((tb + 0) << 10) | cc);
        }
        if (h1) {
          int q = atomicAdd(wc, 1);
          if (q < WCAP) wl[q] = (unsigned)(((tb + 1) << 10) | cc);
        }
        if (h2) {
          int q = atomicAdd(wc, 1);
          if (q < WCAP) wl[q] = (unsigned)(((tb + 2) << 10) | cc);
        }
        if (h3) {
          int q = atomicAdd(wc, 1);
          if (q < WCAP) wl[q] = (unsigned)(((tb + 3) << 10) | cc);
        }
      }
    }
  }

  // Wave-local: drain DS ops (pushes from all lanes of THIS wave), then read.
  asm volatile("s_waitcnt lgkmcnt(0)" ::: "memory");
  int n = *wc;

  // ---- resolution: lanes 0..15 own token wtok+lane ----
  int idxw = 0;
  if (lane < 16) {
    int cnt = 0, code = 0;
    for (int e = 0; e < n && e < WCAP; ++e) {
      unsigned u = wl[e];  // same addr across lanes -> LDS broadcast
      if ((int)(u >> 10) == lane) {
        cnt++;
        code = (int)(u & 1023u);
      }
    }
    if (n > WCAP) {
      // pathological overflow: full exact scan, ascending c, strict '<'
      long long gt = (long long)blockIdx.x * 256 + wtok + lane;
      float sz2v = sz2[wtok + lane];
      float bd = 3.4e38f;
      code = 0;
      for (int c = 0; c < K_CODES; ++c) {
        float d = exact_dist(z, gt, c, w, sz2v, sw2[c]);
        if (d < bd) {
          bd = d;
          code = c;
        }
      }
    } else if (cnt >= 2) {
      // exact lex-(d, idx) min over candidates == numpy first-min-wins
      long long gt = (long long)blockIdx.x * 256 + wtok + lane;
      float sz2v = sz2[wtok + lane];
      float bd = 3.4e38f;
      int bi = K_CODES;
      for (int e = 0; e < n; ++e) {
        unsigned u = wl[e];
        if ((int)(u >> 10) == lane) {
          int c = (int)(u & 1023u);
          float d = exact_dist(z, gt, c, w, sz2v, sw2[c]);
          if (d < bd || (d == bd && c < bi)) {
            bd = d;
            bi = c;
          }
        }
      }
      code = bi;
    }
    idxw = code;
  }
  const int idx = __shfl(idxw, lane >> 2, 64);

  // ---- outputs (per-wave): lane -> (token = wtok + lane>>2, quarter) ----
  {
    const int tok = wtok + (lane >> 2), q = lane & 3;
    const long long gt = (long long)blockIdx.x * 256 + tok;
    const float4* zp = (const float4*)(z + (size_t)gt * DIM) + q * 4;
    const float4* wp = (const float4*)(w + (size_t)idx * DIM) + q * 4;
    float4* op = (float4*)(out + (size_t)gt * DIM) + q * 4;
    double ls = 0.0;
#pragma unroll
    for (int i = 0; i < 4; ++i) {
      float4 wv = wp[i];
      float4 zv = zp[i];
      op[i] = wv;
      double d0 = (double)wv.x - (double)zv.x;
      double d1 = (double)wv.y - (double)zv.y;
      double d2 = (double)wv.z - (double)zv.z;
      double d3 = (double)wv.w - (double)zv.w;
      ls = __builtin_fma(d0, d0, ls);
      ls = __builtin_fma(d1, d1, ls);
      ls = __builtin_fma(d2, d2, ls);
      ls = __builtin_fma(d3, d3, ls);
    }
    if (q == 0) out[OUT_IDX_OFF + gt] = (float)idx;
#pragma unroll
    for (int off = 32; off > 0; off >>= 1) ls += __shfl_down(ls, off, 64);
    if (lane == 0) red[wid] = ls;
  }
  __syncthreads();
  if (tid == 0) {
    double s = 0.0;
#pragma unroll
    for (int i = 0; i < 16; ++i) s += red[i];
    atomicAdd(loss_acc, s);
  }
}

// ---------------- finalize loss ----------------
__global__ void vq_final_k(const double* __restrict__ loss_acc,
                           float* __restrict__ out) {
  out[OUT_LOSS_OFF] =
      (float)(1.25 * (*loss_acc) * (1.0 / (double)((size_t)N_TOK * DIM)));
}

extern "C" void kernel_launch(void* const* d_in, const int* in_sizes, int n_in,
                              void* d_out, int out_size, void* d_ws,
                              size_t ws_size, hipStream_t stream) {
  const float* z = (const float*)d_in[0];
  const float* w = (const float*)d_in[1];
  float* out = (float*)d_out;
  double* loss_acc = (double*)d_ws;  // 8 bytes of ws only (as in R0-R6)

  hipMemsetAsync(d_ws, 0, 8, stream);
  vq_pre_k<<<4, 256, 0, stream>>>(w);
  vq_main_k<<<N_TOK / 256, 1024, 0, stream>>>(z, w, out, loss_acc);
  vq_final_k<<<1, 1, 0, stream>>>(loss_acc, out);
}

// Round 9
// 592.630 us; speedup vs baseline: 1.2004x; 1.2004x over previous
//
#include <hip/hip_runtime.h>
#include <stdint.h>

#define N_TOK 262144
#define DIM 64
#define K_CODES 1024
#define HALF_CODES 512
#define OUT_LOSS_OFF (N_TOK * DIM)      // 16777216
#define OUT_IDX_OFF (N_TOK * DIM + 1)   // 16777217

// Hi-only screen error: |screen - real| <= (2^-11 z-cvt + 2^-11 w-cvt)
// * ||2z||*||w|| + fp32 accum ~ 1.9e-4 (||z|| <= 11.5). Candidate rule
// needs THR > 2*eps_s = 3.8e-4. THR = 6.5e-4 (1.7x headroom).
// Screen works on acch = 1024*(dot - w2) directly (exact pow2 scale,
// order-REVERSED): candidate <=> acch >= M - 1024*THR = M - 0.666.
// Phased halves: pass2(h) pushes vs max-so-far <= global max -> pushed set
// is a SUPERSET of the true candidate set -> cnt==1 still proves argmin.
#define THRA 0.666f
#define WCAP 128

typedef _Float16 half8 __attribute__((ext_vector_type(8)));
typedef float f32x4 __attribute__((ext_vector_type(4)));
typedef unsigned int uint32x4 __attribute__((ext_vector_type(4)));

// ---- LDS layout (byte offsets) ---- total 78 KB -> 2 blocks/CU (156 KB
// of 160) = 8 waves/SIMD (R6's 153KB pinned 1 block = 4 waves: latency-bound,
// no pipe >33%; R8's L2-codebook failed on L2 latency at VGPR=32).
// Codebook half staged per phase in [chunk][code] order: sweep reads are
// 256B-contiguous per 16-lane group -> conflict-free (R6 had 37K conflicts).
#define SM_WF 0           // fp16 half-codebook: 8 chunks x 512 codes x 16B
#define SM_SW2 65536      // float[1024] ||w||^2 (exact, all codes)
#define SM_WL 69632       // u32[16][WCAP] per-wave candidate lists
#define SM_WC 77824       // int[16] per-wave candidate counters
#define SM_RED 77888      // double[16] loss partials
#define SM_BYTES 78016

// numpy pairwise sum of squares over 64 contiguous fp32, STREAMING form:
// identical operation order to the reference pairwise sum (8 accumulators,
// unroll-8, paired combine) but never holds more than 16 values live.
__device__ __forceinline__ float np_sumsq64_stream(const float4* p) {
#pragma clang fp contract(off)
  float r[8];
  {
    float4 a = p[0], b = p[1];
    r[0] = a.x * a.x;
    r[1] = a.y * a.y;
    r[2] = a.z * a.z;
    r[3] = a.w * a.w;
    r[4] = b.x * b.x;
    r[5] = b.y * b.y;
    r[6] = b.z * b.z;
    r[7] = b.w * b.w;
  }
#pragma unroll
  for (int i = 1; i < 8; ++i) {
    float4 a = p[2 * i], b = p[2 * i + 1];
    r[0] += a.x * a.x;
    r[1] += a.y * a.y;
    r[2] += a.z * a.z;
    r[3] += a.w * a.w;
    r[4] += b.x * b.x;
    r[5] += b.y * b.y;
    r[6] += b.z * b.z;
    r[7] += b.w * b.w;
  }
  return ((r[0] + r[1]) + (r[2] + r[3])) + ((r[4] + r[5]) + (r[6] + r[7]));
}

// The ORIGINAL bit-exact distance: d = fl(fl(s_z2+s_w2) - chain64((2z)*w)),
// sequential ascending k. Matches numpy/BLAS exactly -> argmin-identical.
__device__ __forceinline__ float exact_dist(const float* __restrict__ z,
                                            long long t, int c,
                                            const float* __restrict__ w,
                                            float s_z2v, float w2) {
  const float4* zp = (const float4*)(z + (size_t)t * DIM);
  const float4* wp = (const float4*)(w + (size_t)c * DIM);
  float a = 0.f;
#pragma unroll
  for (int i = 0; i < 16; ++i) {
    float4 zv = zp[i];
    float4 pv = wp[i];
    a = __builtin_fmaf(zv.x + zv.x, pv.x, a);
    a = __builtin_fmaf(zv.y + zv.y, pv.y, a);
    a = __builtin_fmaf(zv.z + zv.z, pv.z, a);
    a = __builtin_fmaf(zv.w + zv.w, pv.w, a);
  }
  return (s_z2v + w2) - a;
}

// Hi-only MFMA A-frag from 8 z floats: fp16(2z).
__device__ __forceinline__ void make_afrag_hi(float4 a, float4 b, half8& hi) {
  float v[8] = {a.x, a.y, a.z, a.w, b.x, b.y, b.z, b.w};
  uint32x4 uh;
#pragma unroll
  for (int j = 0; j < 4; ++j) {
    _Float16 h0 = (_Float16)(v[2 * j] + v[2 * j]);
    _Float16 h1 = (_Float16)(v[2 * j + 1] + v[2 * j + 1]);
    uh[j] = (unsigned)__builtin_bit_cast(unsigned short, h0) |
            ((unsigned)__builtin_bit_cast(unsigned short, h1) << 16);
  }
  hi = __builtin_bit_cast(half8, uh);
}

// ---------------- main: 256 tokens / 1024 threads / 16 waves ----------------
// Phased two-pass MFMA screen: per codebook half {stage fp16 -> P1 max ->
// butterfly -> P2 bit-identical recompute + candidate push}, then wave-local
// exact resolution. 8 waves/SIMD; conflict-free LDS reads; lazy sz2.
__global__ __attribute__((amdgpu_flat_work_group_size(1024, 1024),
                          amdgpu_waves_per_eu(8, 8))) void vq_main_k(
    const float* __restrict__ z, const float* __restrict__ w,
    float* __restrict__ out, double* __restrict__ loss_acc) {
#pragma clang fp contract(off)
  __shared__ __align__(16) char smem[SM_BYTES];
  char* wf = smem + SM_WF;
  float* sw2 = (float*)(smem + SM_SW2);
  double* red = (double*)(smem + SM_RED);

  const int tid = (int)threadIdx.x;
  const int lane = tid & 63;
  const int wid = tid >> 6;  // 16 waves

  unsigned* wl = (unsigned*)(smem + SM_WL) + wid * WCAP;
  int* wc = (int*)(smem + SM_WC) + wid;
  if (lane == 0) *wc = 0;

  // ---- prologue: ||w||^2 for all 1024 codes (exact pairwise order) ----
  {
    const float4* wp = (const float4*)(w + (size_t)tid * DIM);
    sw2[tid] = np_sumsq64_stream(wp);
  }

  // ---- A-frags (z): token = wtok + c15, k = g*8 and 32+g*8 ----
  const int wtok = wid * 16;
  const int g = lane >> 4;    // k-group
  const int c15 = lane & 15;  // code-within-tile
  half8 ah0, ah1;
  {
    long long gA = ((long long)blockIdx.x * 256 + wtok + c15) * DIM;
    const float* zr = z + gA + g * 8;
    make_afrag_hi(*(const float4*)(zr), *(const float4*)(zr + 4), ah0);
    make_afrag_hi(*(const float4*)(zr + 32), *(const float4*)(zr + 36), ah1);
  }
  // sweep-read bases: chunk g and 4+g of the staged half
  const char* b0base = wf + g * 8192;
  const char* b1base = wf + (4 + g) * 8192;

  float M1[4];
#pragma unroll
  for (int r = 0; r < 4; ++r) M1[r] = -3.4e38f;
  const int tb = g * 4;

#pragma unroll 1
  for (int h = 0; h < 2; ++h) {
    // protect wf: all waves done with previous half before overwrite
    __syncthreads();
    // ---- stage half h: 2 threads per code, [chunk][code] layout ----
    {
      const int cl = tid >> 1;   // code-local 0..511
      const int hf = tid & 1;    // k-half of the row
      const float4* wp =
          (const float4*)(w + (size_t)(h * HALF_CODES + cl) * DIM) + hf * 8;
#pragma unroll
      for (int c4 = 0; c4 < 4; ++c4) {
        float4 a = wp[2 * c4], b = wp[2 * c4 + 1];
        float x[8] = {a.x, a.y, a.z, a.w, b.x, b.y, b.z, b.w};
        uint32x4 pk;
#pragma unroll
        for (int j = 0; j < 4; ++j) {
          _Float16 h0 = (_Float16)(x[2 * j] * 1024.f);
          _Float16 h1 = (_Float16)(x[2 * j + 1] * 1024.f);
          pk[j] = (unsigned)__builtin_bit_cast(unsigned short, h0) |
                  ((unsigned)__builtin_bit_cast(unsigned short, h1) << 16);
        }
        *(uint32x4*)(wf + (hf * 4 + c4) * 8192 + cl * 16) = pk;
      }
    }
    __syncthreads();

    // ---- pass 1 over this half: per-token running max of acch ----
#pragma unroll 4
    for (int ct = 0; ct < 32; ++ct) {
      const int ccl = (ct << 4) | c15;           // code-local in half
      float w2c = sw2[(h << 9) | ccl];
      half8 b0 =
          __builtin_bit_cast(half8, *(const uint32x4*)(b0base + ccl * 16));
      half8 b1 =
          __builtin_bit_cast(half8, *(const uint32x4*)(b1base + ccl * 16));
      float vm = w2c * -1024.f;  // exact (pow2 scale)
      f32x4 acch = {vm, vm, vm, vm};
      acch = __builtin_amdgcn_mfma_f32_16x16x32_f16(ah0, b0, acch, 0, 0, 0);
      acch = __builtin_amdgcn_mfma_f32_16x16x32_f16(ah1, b1, acch, 0, 0, 0);
#pragma unroll
      for (int r = 0; r < 4; ++r) M1[r] = fmaxf(M1[r], acch[r]);
    }
    // butterfly all-reduce max over the 16 lanes sharing these token rows
#pragma unroll
    for (int s = 1; s <= 8; s <<= 1) {
#pragma unroll
      for (int r = 0; r < 4; ++r)
        M1[r] = fmaxf(M1[r], __shfl_xor(M1[r], s, 64));
    }
    float thr[4];
#pragma unroll
    for (int r = 0; r < 4; ++r) thr[r] = M1[r] - THRA;

    // ---- pass 2: bit-identical recompute; push (tokloc<<10)|code ----
#pragma unroll 2
    for (int ct = 0; ct < 32; ++ct) {
      const int ccl = (ct << 4) | c15;
      const int cc = (h << 9) | ccl;             // global code id
      float w2c = sw2[cc];
      half8 b0 =
          __builtin_bit_cast(half8, *(const uint32x4*)(b0base + ccl * 16));
      half8 b1 =
          __builtin_bit_cast(half8, *(const uint32x4*)(b1base + ccl * 16));
      float vm = w2c * -1024.f;
      f32x4 acch = {vm, vm, vm, vm};
      acch = __builtin_amdgcn_mfma_f32_16x16x32_f16(ah0, b0, acch, 0, 0, 0);
      acch = __builtin_amdgcn_mfma_f32_16x16x32_f16(ah1, b1, acch, 0, 0, 0);
      bool h0 = acch[0] >= thr[0];
      bool h1 = acch[1] >= thr[1];
      bool h2 = acch[2] >= thr[2];
      bool h3 = acch[3] >= thr[3];
      if (h0 | h1 | h2 | h3) {  // execz-skip in the common case
        if (h0) {
          int q = atomicAdd(wc, 1);
          if (q < WCAP) wl[q] = (unsigned)(((tb + 0) << 10) | cc);
        }
        if (h1) {
          int q = atomicAdd(wc, 1);
          if (q < WCAP) wl[q] = (unsigned)(((tb + 1) << 10) | cc);
        }
        if (h2) {
          int q = atomicAdd(wc, 1);
          if (q < WCAP) wl[q] = (unsigned)(((tb + 2) << 10) | cc);
        }
        if (h3) {
          int q = atomicAdd(wc, 1);
          if (q < WCAP) wl[q] = (unsigned)(((tb + 3) << 10) | cc);
        }
      }
    }
  }

  // Wave-local: drain DS ops (pushes from all lanes of THIS wave), then read.
  asm volatile("s_waitcnt lgkmcnt(0)" ::: "memory");
  int n = *wc;

  // ---- resolution: lanes 0..15 own token wtok+lane (lazy sz2) ----
  int idxw = 0;
  if (lane < 16) {
    int cnt = 0, code = 0;
    for (int e = 0; e < n && e < WCAP; ++e) {
      unsigned u = wl[e];  // same addr across lanes -> LDS broadcast
      if ((int)(u >> 10) == lane) {
        cnt++;
        code = (int)(u & 1023u);
      }
    }
    if (n > WCAP) {
      // pathological overflow: full exact scan, ascending c, strict '<'
      long long gt = (long long)blockIdx.x * 256 + wtok + lane;
      float sz2v = np_sumsq64_stream((const float4*)(z + (size_t)gt * DIM));
      float bd = 3.4e38f;
      code = 0;
      for (int c = 0; c < K_CODES; ++c) {
        float d = exact_dist(z, gt, c, w, sz2v, sw2[c]);
        if (d < bd) {
          bd = d;
          code = c;
        }
      }
    } else if (cnt >= 2) {
      // exact lex-(d, idx) min over candidates == numpy first-min-wins
      long long gt = (long long)blockIdx.x * 256 + wtok + lane;
      float sz2v = np_sumsq64_stream((const float4*)(z + (size_t)gt * DIM));
      float bd = 3.4e38f;
      int bi = K_CODES;
      for (int e = 0; e < n; ++e) {
        unsigned u = wl[e];
        if ((int)(u >> 10) == lane) {
          int c = (int)(u & 1023u);
          float d = exact_dist(z, gt, c, w, sz2v, sw2[c]);
          if (d < bd || (d == bd && c < bi)) {
            bd = d;
            bi = c;
          }
        }
      }
      code = bi;
    }
    idxw = code;
  }
  const int idx = __shfl(idxw, lane >> 2, 64);

  // ---- outputs (per-wave): lane -> (token = wtok + lane>>2, quarter) ----
  {
    const int tok = wtok + (lane >> 2), q = lane & 3;
    const long long gt = (long long)blockIdx.x * 256 + tok;
    const float4* zp = (const float4*)(z + (size_t)gt * DIM) + q * 4;
    const float4* wp = (const float4*)(w + (size_t)idx * DIM) + q * 4;
    float4* op = (float4*)(out + (size_t)gt * DIM) + q * 4;
    double ls = 0.0;
#pragma unroll
    for (int i = 0; i < 4; ++i) {
      float4 wv = wp[i];
      float4 zv = zp[i];
      op[i] = wv;
      double d0 = (double)wv.x - (double)zv.x;
      double d1 = (double)wv.y - (double)zv.y;
      double d2 = (double)wv.z - (double)zv.z;
      double d3 = (double)wv.w - (double)zv.w;
      ls = __builtin_fma(d0, d0, ls);
      ls = __builtin_fma(d1, d1, ls);
      ls = __builtin_fma(d2, d2, ls);
      ls = __builtin_fma(d3, d3, ls);
    }
    if (q == 0) out[OUT_IDX_OFF + gt] = (float)idx;
#pragma unroll
    for (int off = 32; off > 0; off >>= 1) ls += __shfl_down(ls, off, 64);
    if (lane == 0) red[wid] = ls;
  }
  __syncthreads();
  if (tid == 0) {
    double s = 0.0;
#pragma unroll
    for (int i = 0; i < 16; ++i) s += red[i];
    atomicAdd(loss_acc, s);
  }
}

// ---------------- finalize loss ----------------
__global__ void vq_final_k(const double* __restrict__ loss_acc,
                           float* __restrict__ out) {
  out[OUT_LOSS_OFF] =
      (float)(1.25 * (*loss_acc) * (1.0 / (double)((size_t)N_TOK * DIM)));
}

extern "C" void kernel_launch(void* const* d_in, const int* in_sizes, int n_in,
                              void* d_out, int out_size, void* d_ws,
                              size_t ws_size, hipStream_t stream) {
  const float* z = (const float*)d_in[0];
  const float* w = (const float*)d_in[1];
  float* out = (float*)d_out;
  double* loss_acc = (double*)d_ws;  // 8 bytes of ws only

  hipMemsetAsync(d_ws, 0, 8, stream);
  vq_main_k<<<N_TOK / 256, 1024, 0, stream>>>(z, w, out, loss_acc);
  vq_final_k<<<1, 1, 0, stream>>>(loss_acc, out);
}

// Round 10
// 460.574 us; speedup vs baseline: 1.5445x; 1.2867x over previous
//
#include <hip/hip_runtime.h>
#include <stdint.h>

#define N_TOK 262144
#define DIM 64
#define K_CODES 1024
#define HALF_CODES 512
#define OUT_LOSS_OFF (N_TOK * DIM)      // 16777216
#define OUT_IDX_OFF (N_TOK * DIM + 1)   // 16777217

// Hi-only screen error: |screen - real| <= (2^-11 z-cvt + 2^-11 w-cvt)
// * ||2z||*||w|| + fp32 accum ~ 1.9e-4 (||z|| <= 11.5). Candidate rule
// needs THR > 2*eps_s = 3.8e-4. THR = 6.5e-4 (1.7x headroom).
// Screen works on acch = 1024*(dot - w2) directly (exact pow2 scale,
// order-REVERSED): candidate <=> acch >= M - 1024*THR = M - 0.666.
// Phased halves: pass2(h) pushes vs max-so-far <= global max -> pushed set
// is a SUPERSET of the true candidate set -> cnt==1 still proves argmin
// (the true argmin always clears its half's threshold: 0.666 > 1024*2eps).
#define THRA 0.666f
#define WCAP 128

typedef _Float16 half8 __attribute__((ext_vector_type(8)));
typedef float f32x4 __attribute__((ext_vector_type(4)));
typedef unsigned int uint32x4 __attribute__((ext_vector_type(4)));

// ---- LDS layout (byte offsets) ---- total 78 KB -> 2 blocks/CU (156 KB
// of 160) = 8 waves/SIMD, IF VGPR <= 64.
// R10 allocator law (3 data points): waves_per_eu(8,8) -> VGPR=32 (forced
// minimize -> R9 spilled 83MB scratch); (4,4) -> 52-64 natural; (2,4) -> 68.
// So: min=4 (128-reg budget, no spill pressure), max=8 (worth staying <=64).
#define SM_WF 0           // fp16 half-codebook: 8 chunks x 512 codes x 16B
#define SM_SW2 65536      // float[1024] ||w||^2 (exact, all codes)
#define SM_WL 69632       // u32[16][WCAP] per-wave candidate lists
#define SM_WC 77824       // int[16] per-wave candidate counters
#define SM_RED 77888      // double[16] loss partials
#define SM_BYTES 78016

// numpy pairwise sum of squares over 64 contiguous fp32, STREAMING form:
// identical operation order to the reference pairwise sum (8 accumulators,
// unroll-8, paired combine) but never holds more than 16 values live.
__device__ __forceinline__ float np_sumsq64_stream(const float4* p) {
#pragma clang fp contract(off)
  float r[8];
  {
    float4 a = p[0], b = p[1];
    r[0] = a.x * a.x;
    r[1] = a.y * a.y;
    r[2] = a.z * a.z;
    r[3] = a.w * a.w;
    r[4] = b.x * b.x;
    r[5] = b.y * b.y;
    r[6] = b.z * b.z;
    r[7] = b.w * b.w;
  }
#pragma unroll
  for (int i = 1; i < 8; ++i) {
    float4 a = p[2 * i], b = p[2 * i + 1];
    r[0] += a.x * a.x;
    r[1] += a.y * a.y;
    r[2] += a.z * a.z;
    r[3] += a.w * a.w;
    r[4] += b.x * b.x;
    r[5] += b.y * b.y;
    r[6] += b.z * b.z;
    r[7] += b.w * b.w;
  }
  return ((r[0] + r[1]) + (r[2] + r[3])) + ((r[4] + r[5]) + (r[6] + r[7]));
}

// The ORIGINAL bit-exact distance: d = fl(fl(s_z2+s_w2) - chain64((2z)*w)),
// sequential ascending k. Matches numpy/BLAS exactly -> argmin-identical.
__device__ __forceinline__ float exact_dist(const float* __restrict__ z,
                                            long long t, int c,
                                            const float* __restrict__ w,
                                            float s_z2v, float w2) {
  const float4* zp = (const float4*)(z + (size_t)t * DIM);
  const float4* wp = (const float4*)(w + (size_t)c * DIM);
  float a = 0.f;
#pragma unroll
  for (int i = 0; i < 16; ++i) {
    float4 zv = zp[i];
    float4 pv = wp[i];
    a = __builtin_fmaf(zv.x + zv.x, pv.x, a);
    a = __builtin_fmaf(zv.y + zv.y, pv.y, a);
    a = __builtin_fmaf(zv.z + zv.z, pv.z, a);
    a = __builtin_fmaf(zv.w + zv.w, pv.w, a);
  }
  return (s_z2v + w2) - a;
}

// Hi-only MFMA A-frag from 8 z floats: fp16(2z).
__device__ __forceinline__ void make_afrag_hi(float4 a, float4 b, half8& hi) {
  float v[8] = {a.x, a.y, a.z, a.w, b.x, b.y, b.z, b.w};
  uint32x4 uh;
#pragma unroll
  for (int j = 0; j < 4; ++j) {
    _Float16 h0 = (_Float16)(v[2 * j] + v[2 * j]);
    _Float16 h1 = (_Float16)(v[2 * j + 1] + v[2 * j + 1]);
    uh[j] = (unsigned)__builtin_bit_cast(unsigned short, h0) |
            ((unsigned)__builtin_bit_cast(unsigned short, h1) << 16);
  }
  hi = __builtin_bit_cast(half8, uh);
}

// ---------------- main: 256 tokens / 1024 threads / 16 waves ----------------
// Phased two-pass MFMA screen: per codebook half {stage fp16 -> P1 max ->
// butterfly -> P2 bit-identical recompute + candidate push}, then wave-local
// exact resolution. Target: 8 waves/SIMD, conflict-balanced LDS, no spills.
__global__ __attribute__((amdgpu_flat_work_group_size(1024, 1024),
                          amdgpu_waves_per_eu(4, 8))) void vq_main_k(
    const float* __restrict__ z, const float* __restrict__ w,
    float* __restrict__ out, double* __restrict__ loss_acc) {
#pragma clang fp contract(off)
  __shared__ __align__(16) char smem[SM_BYTES];
  char* wf = smem + SM_WF;
  float* sw2 = (float*)(smem + SM_SW2);
  double* red = (double*)(smem + SM_RED);

  const int tid = (int)threadIdx.x;
  const int lane = tid & 63;
  const int wid = tid >> 6;  // 16 waves

  unsigned* wl = (unsigned*)(smem + SM_WL) + wid * WCAP;
  int* wc = (int*)(smem + SM_WC) + wid;
  if (lane == 0) *wc = 0;

  // ---- prologue: ||w||^2 for all 1024 codes (exact pairwise order) ----
  {
    const float4* wp = (const float4*)(w + (size_t)tid * DIM);
    sw2[tid] = np_sumsq64_stream(wp);
  }

  // ---- A-frags (z): token = wtok + c15, k = g*8 and 32+g*8 ----
  const int wtok = wid * 16;
  const int g = lane >> 4;    // k-group
  const int c15 = lane & 15;  // code-within-tile
  half8 ah0, ah1;
  {
    long long gA = ((long long)blockIdx.x * 256 + wtok + c15) * DIM;
    const float* zr = z + gA + g * 8;
    make_afrag_hi(*(const float4*)(zr), *(const float4*)(zr + 4), ah0);
    make_afrag_hi(*(const float4*)(zr + 32), *(const float4*)(zr + 36), ah1);
  }
  // sweep-read bases: chunk g and 4+g of the staged half
  const char* b0base = wf + g * 8192;
  const char* b1base = wf + (4 + g) * 8192;

  float M1[4];
#pragma unroll
  for (int r = 0; r < 4; ++r) M1[r] = -3.4e38f;
  const int tb = g * 4;

#pragma unroll 1
  for (int h = 0; h < 2; ++h) {
    // protect wf: all waves done with previous half before overwrite
    __syncthreads();
    // ---- stage half h: 2 threads per code, [chunk][code] layout ----
    {
      const int cl = tid >> 1;   // code-local 0..511
      const int hf = tid & 1;    // k-half of the row
      const float4* wp =
          (const float4*)(w + (size_t)(h * HALF_CODES + cl) * DIM) + hf * 8;
#pragma unroll
      for (int c4 = 0; c4 < 4; ++c4) {
        float4 a = wp[2 * c4], b = wp[2 * c4 + 1];
        float x[8] = {a.x, a.y, a.z, a.w, b.x, b.y, b.z, b.w};
        uint32x4 pk;
#pragma unroll
        for (int j = 0; j < 4; ++j) {
          _Float16 h0 = (_Float16)(x[2 * j] * 1024.f);
          _Float16 h1 = (_Float16)(x[2 * j + 1] * 1024.f);
          pk[j] = (unsigned)__builtin_bit_cast(unsigned short, h0) |
                  ((unsigned)__builtin_bit_cast(unsigned short, h1) << 16);
        }
        *(uint32x4*)(wf + (hf * 4 + c4) * 8192 + cl * 16) = pk;
      }
    }
    __syncthreads();

    // ---- pass 1 over this half: per-token running max of acch ----
#pragma unroll 4
    for (int ct = 0; ct < 32; ++ct) {
      const int ccl = (ct << 4) | c15;           // code-local in half
      float w2c = sw2[(h << 9) | ccl];
      half8 b0 =
          __builtin_bit_cast(half8, *(const uint32x4*)(b0base + ccl * 16));
      half8 b1 =
          __builtin_bit_cast(half8, *(const uint32x4*)(b1base + ccl * 16));
      float vm = w2c * -1024.f;  // exact (pow2 scale)
      f32x4 acch = {vm, vm, vm, vm};
      acch = __builtin_amdgcn_mfma_f32_16x16x32_f16(ah0, b0, acch, 0, 0, 0);
      acch = __builtin_amdgcn_mfma_f32_16x16x32_f16(ah1, b1, acch, 0, 0, 0);
#pragma unroll
      for (int r = 0; r < 4; ++r) M1[r] = fmaxf(M1[r], acch[r]);
    }
    // butterfly all-reduce max over the 16 lanes sharing these token rows
#pragma unroll
    for (int s = 1; s <= 8; s <<= 1) {
#pragma unroll
      for (int r = 0; r < 4; ++r)
        M1[r] = fmaxf(M1[r], __shfl_xor(M1[r], s, 64));
    }
    float thr[4];
#pragma unroll
    for (int r = 0; r < 4; ++r) thr[r] = M1[r] - THRA;

    // ---- pass 2: bit-identical recompute; push (tokloc<<10)|code ----
#pragma unroll 2
    for (int ct = 0; ct < 32; ++ct) {
      const int ccl = (ct << 4) | c15;
      const int cc = (h << 9) | ccl;             // global code id
      float w2c = sw2[cc];
      half8 b0 =
          __builtin_bit_cast(half8, *(const uint32x4*)(b0base + ccl * 16));
      half8 b1 =
          __builtin_bit_cast(half8, *(const uint32x4*)(b1base + ccl * 16));
      float vm = w2c * -1024.f;
      f32x4 acch = {vm, vm, vm, vm};
      acch = __builtin_amdgcn_mfma_f32_16x16x32_f16(ah0, b0, acch, 0, 0, 0);
      acch = __builtin_amdgcn_mfma_f32_16x16x32_f16(ah1, b1, acch, 0, 0, 0);
      bool h0 = acch[0] >= thr[0];
      bool h1 = acch[1] >= thr[1];
      bool h2 = acch[2] >= thr[2];
      bool h3 = acch[3] >= thr[3];
      if (h0 | h1 | h2 | h3) {  // execz-skip in the common case
        if (h0) {
          int q = atomicAdd(wc, 1);
          if (q < WCAP) wl[q] = (unsigned)(((tb + 0) << 10) | cc);
        }
        if (h1) {
          int q = atomicAdd(wc, 1);
          if (q < WCAP) wl[q] = (unsigned)(((tb + 1) << 10) | cc);
        }
        if (h2) {
          int q = atomicAdd(wc, 1);
          if (q < WCAP) wl[q] = (unsigned)(((tb + 2) << 10) | cc);
        }
        if (h3) {
          int q = atomicAdd(wc, 1);
          if (q < WCAP) wl[q] = (unsigned)(((tb + 3) << 10) | cc);
        }
      }
    }
  }

  // Wave-local: drain DS ops (pushes from all lanes of THIS wave), then read.
  asm volatile("s_waitcnt lgkmcnt(0)" ::: "memory");
  int n = *wc;

  // ---- resolution: lanes 0..15 own token wtok+lane (lazy sz2) ----
  int idxw = 0;
  if (lane < 16) {
    int cnt = 0, code = 0;
    for (int e = 0; e < n && e < WCAP; ++e) {
      unsigned u = wl[e];  // same addr across lanes -> LDS broadcast
      if ((int)(u >> 10) == lane) {
        cnt++;
        code = (int)(u & 1023u);
      }
    }
    if (n > WCAP) {
      // pathological overflow: full exact scan, ascending c, strict '<'
      long long gt = (long long)blockIdx.x * 256 + wtok + lane;
      float sz2v = np_sumsq64_stream((const float4*)(z + (size_t)gt * DIM));
      float bd = 3.4e38f;
      code = 0;
      for (int c = 0; c < K_CODES; ++c) {
        float d = exact_dist(z, gt, c, w, sz2v, sw2[c]);
        if (d < bd) {
          bd = d;
          code = c;
        }
      }
    } else if (cnt >= 2) {
      // exact lex-(d, idx) min over candidates == numpy first-min-wins
      long long gt = (long long)blockIdx.x * 256 + wtok + lane;
      float sz2v = np_sumsq64_stream((const float4*)(z + (size_t)gt * DIM));
      float bd = 3.4e38f;
      int bi = K_CODES;
      for (int e = 0; e < n; ++e) {
        unsigned u = wl[e];
        if ((int)(u >> 10) == lane) {
          int c = (int)(u & 1023u);
          float d = exact_dist(z, gt, c, w, sz2v, sw2[c]);
          if (d < bd || (d == bd && c < bi)) {
            bd = d;
            bi = c;
          }
        }
      }
      code = bi;
    }
    idxw = code;
  }
  const int idx = __shfl(idxw, lane >> 2, 64);

  // ---- outputs (per-wave): lane -> (token = wtok + lane>>2, quarter) ----
  {
    const int tok = wtok + (lane >> 2), q = lane & 3;
    const long long gt = (long long)blockIdx.x * 256 + tok;
    const float4* zp = (const float4*)(z + (size_t)gt * DIM) + q * 4;
    const float4* wp = (const float4*)(w + (size_t)idx * DIM) + q * 4;
    float4* op = (float4*)(out + (size_t)gt * DIM) + q * 4;
    double ls = 0.0;
#pragma unroll
    for (int i = 0; i < 4; ++i) {
      float4 wv = wp[i];
      float4 zv = zp[i];
      op[i] = wv;
      double d0 = (double)wv.x - (double)zv.x;
      double d1 = (double)wv.y - (double)zv.y;
      double d2 = (double)wv.z - (double)zv.z;
      double d3 = (double)wv.w - (double)zv.w;
      ls = __builtin_fma(d0, d0, ls);
      ls = __builtin_fma(d1, d1, ls);
      ls = __builtin_fma(d2, d2, ls);
      ls = __builtin_fma(d3, d3, ls);
    }
    if (q == 0) out[OUT_IDX_OFF + gt] = (float)idx;
#pragma unroll
    for (int off = 32; off > 0; off >>= 1) ls += __shfl_down(ls, off, 64);
    if (lane == 0) red[wid] = ls;
  }
  __syncthreads();
  if (tid == 0) {
    double s = 0.0;
#pragma unroll
    for (int i = 0; i < 16; ++i) s += red[i];
    atomicAdd(loss_acc, s);
  }
}

// ---------------- finalize loss ----------------
__global__ void vq_final_k(const double* __restrict__ loss_acc,
                           float* __restrict__ out) {
  out[OUT_LOSS_OFF] =
      (float)(1.25 * (*loss_acc) * (1.0 / (double)((size_t)N_TOK * DIM)));
}

extern "C" void kernel_launch(void* const* d_in, const int* in_sizes, int n_in,
                              void* d_out, int out_size, void* d_ws,
                              size_t ws_size, hipStream_t stream) {
  const float* z = (const float*)d_in[0];
  const float* w = (const float*)d_in[1];
  float* out = (float*)d_out;
  double* loss_acc = (double*)d_ws;  // 8 bytes of ws only

  hipMemsetAsync(d_ws, 0, 8, stream);
  vq_main_k<<<N_TOK / 256, 1024, 0, stream>>>(z, w, out, loss_acc);
  vq_final_k<<<1, 1, 0, stream>>>(loss_acc, out);
}